// Round 4
// baseline (632.290 us; speedup 1.0000x reference)
//
#include <hip/hip_runtime.h>
#include <math.h>

#define NNODES 50000
#define NEDGES 800000

using short8 = __attribute__((ext_vector_type(8))) short;   // 8 bf16 = 4 VGPRs
using f32x4  = __attribute__((ext_vector_type(4))) float;   // MFMA accumulator

// fp32 -> bf16 round-to-nearest-even
__device__ __forceinline__ short f2b(float v) {
    unsigned u = __builtin_bit_cast(unsigned, v);
    u = (u + 0x7FFFu + ((u >> 16) & 1u)) >> 16;
    return (short)u;
}

__device__ __forceinline__ unsigned pk2(short a, short b) {
    return (unsigned)(unsigned short)a | ((unsigned)(unsigned short)b << 16);
}

// ---- prep: pack W1/W2 to bf16 fragment order (lane=non-K idx, 8 contiguous K) ----
__global__ void prep_w(const float* __restrict__ W1, const float* __restrict__ W2,
                       short* __restrict__ wpk) {
    int i = blockIdx.x * 256 + threadIdx.x;
    if (i < 40960) {            // W1 [k<160][n<256]
        int k = i >> 8, n = i & 255;
        wpk[((n >> 4) * 20 + (k >> 3)) * 128 + (n & 15) * 8 + (k & 7)] = f2b(W1[i]);
    }
    if (i < 16384) {            // W2 [k<256][n<64]
        int k = i >> 6, n = i & 63;
        wpk[40960 + ((n >> 4) * 32 + (k >> 3)) * 128 + (n & 15) * 8 + (k & 7)] = f2b(W2[i]);
    }
}

// ---- CSR build ----
__global__ void csr_count(const int* __restrict__ ei, unsigned* __restrict__ cnt) {
    int e = blockIdx.x * 256 + threadIdx.x;
    if (e < NEDGES) atomicAdd(&cnt[ei[e]], 1u);
}

// inclusive scan per 1024-block; block totals to bsum
__global__ __launch_bounds__(1024)
void csr_scan1(const unsigned* __restrict__ cnt, unsigned* __restrict__ offs,
               unsigned* __restrict__ bsum) {
    __shared__ unsigned sbuf[1024];
    int t = threadIdx.x, i = blockIdx.x * 1024 + t;
    unsigned v = (i < NNODES) ? cnt[i] : 0u;
    sbuf[t] = v;
    __syncthreads();
    for (int off = 1; off < 1024; off <<= 1) {
        unsigned add = (t >= off) ? sbuf[t - off] : 0u;
        __syncthreads();
        sbuf[t] += add;
        __syncthreads();
    }
    if (i < NNODES) offs[i] = sbuf[t];          // inclusive, fixed up in scan3
    if (t == 1023) bsum[blockIdx.x] = sbuf[1023];
}

// exclusive scan of the 49 block totals (single wave)
__global__ void csr_scan2(unsigned* __restrict__ bsum) {
    int t = threadIdx.x;
    unsigned v = (t < 49) ? bsum[t] : 0u;
    unsigned orig = v;
    for (int off = 1; off < 64; off <<= 1) {
        unsigned n = __shfl_up(v, off, 64);
        if (t >= off) v += n;
    }
    if (t < 49) bsum[t] = v - orig;             // exclusive
}

// inclusive -> exclusive + add block base; offs[NNODES] = NEDGES
__global__ __launch_bounds__(1024)
void csr_scan3(const unsigned* __restrict__ cnt, unsigned* __restrict__ offs,
               const unsigned* __restrict__ bsum) {
    int i = blockIdx.x * 1024 + threadIdx.x;
    if (i < NNODES)       offs[i] = offs[i] - cnt[i] + bsum[blockIdx.x];
    else if (i == NNODES) offs[i] = NEDGES;
}

__global__ void csr_place(const int* __restrict__ ei, const unsigned* __restrict__ offs,
                          unsigned* __restrict__ cur, unsigned* __restrict__ elist) {
    int e = blockIdx.x * 256 + threadIdx.x;
    if (e < NEDGES) {
        int r = ei[e];
        unsigned p = offs[r] + atomicAdd(&cur[r], 1u);
        elist[p] = (unsigned)e;
    }
}

// ---- main MLP: 4 waves/block, 32 edges/wave, no atomics, no LDS weights ----
__global__ __launch_bounds__(256, 6)
void edgeconv_main(const float* __restrict__ x, const int* __restrict__ ei,
                   const float* __restrict__ ea, const short* __restrict__ wpk,
                   const float* __restrict__ b1, const float* __restrict__ b2,
                   float* __restrict__ outbuf)
{
    __shared__ char hbuf[4][32 * 80];   // 10,240 B: per-wave 32x32 h tile, 80-B stride

    const int tid  = threadIdx.x;
    const int wave = tid >> 6, lane = tid & 63;
    const int l16 = lane & 15, lg = lane >> 4;
    char* hw = hbuf[wave];
    const short* w2a = wpk + 40960;

    const int ebase = (blockIdx.x * 4 + wave) * 32;

    // ---- gather feats as GEMM1 B-fragments (col=edge=l16, k=lg*8..) ----
    short8 fx[2][5];
    #pragma unroll
    for (int nf = 0; nf < 2; ++nf) {
        int e = ebase + nf * 16 + l16;
        int r = ei[e], cc = ei[NEDGES + e];
        #pragma unroll
        for (int seg = 0; seg < 4; ++seg) {     // 2 k-chunks of x[row], 2 of x[col]
            const float* src = x + (seg < 2 ? r : cc) * 64 + (seg & 1) * 32 + lg * 8;
            float4 va = reinterpret_cast<const float4*>(src)[0];
            float4 vb = reinterpret_cast<const float4*>(src)[1];
            short8 f;
            f[0]=f2b(va.x); f[1]=f2b(va.y); f[2]=f2b(va.z); f[3]=f2b(va.w);
            f[4]=f2b(vb.x); f[5]=f2b(vb.y); f[6]=f2b(vb.z); f[7]=f2b(vb.w);
            fx[nf][seg] = f;
        }
        const float4* eap = reinterpret_cast<const float4*>(ea + e * 32 + lg * 8);
        float4 va = eap[0], vb = eap[1];
        short8 f;
        f[0]=f2b(va.x); f[1]=f2b(va.y); f[2]=f2b(va.z); f[3]=f2b(va.w);
        f[4]=f2b(vb.x); f[5]=f2b(vb.y); f[6]=f2b(vb.z); f[7]=f2b(vb.w);
        fx[nf][4] = f;
    }

    f32x4 acc2[4][2] = {};   // [outcol-tile mt2][edge-tile nf]

    #pragma unroll 1
    for (int hp = 0; hp < 8; ++hp) {     // 8 phases of 32 H-cols
        // ---- GEMM1: h^T tile = W1^T @ feats^T (weight frags from L1/L2) ----
        f32x4 acc1[2][2] = {};
        #pragma unroll
        for (int kk = 0; kk < 5; ++kk) {
            #pragma unroll
            for (int mt = 0; mt < 2; ++mt) {
                int nt = hp * 2 + mt;
                short8 wf = *reinterpret_cast<const short8*>(
                    wpk + (nt * 20 + kk * 4 + lg) * 128 + l16 * 8);
                acc1[mt][0] = __builtin_amdgcn_mfma_f32_16x16x32_bf16(wf, fx[0][kk], acc1[mt][0], 0, 0, 0);
                acc1[mt][1] = __builtin_amdgcn_mfma_f32_16x16x32_bf16(wf, fx[1][kk], acc1[mt][1], 0, 0, 0);
            }
        }
        // ---- bias + ReLU + pack: 8-B LDS writes, h[edge][hcol] k-contiguous ----
        #pragma unroll
        for (int mt = 0; mt < 2; ++mt) {
            float4 bb = *reinterpret_cast<const float4*>(b1 + hp * 32 + mt * 16 + lg * 4);
            #pragma unroll
            for (int nf = 0; nf < 2; ++nf) {
                float v0 = fmaxf(acc1[mt][nf][0] + bb.x, 0.0f);
                float v1 = fmaxf(acc1[mt][nf][1] + bb.y, 0.0f);
                float v2 = fmaxf(acc1[mt][nf][2] + bb.z, 0.0f);
                float v3 = fmaxf(acc1[mt][nf][3] + bb.w, 0.0f);
                unsigned long long p =
                    (unsigned long long)pk2(f2b(v0), f2b(v1)) |
                    ((unsigned long long)pk2(f2b(v2), f2b(v3)) << 32);
                *reinterpret_cast<unsigned long long*>(
                    hw + (nf * 16 + l16) * 80 + mt * 32 + lg * 8) = p;
            }
        }
        // in-wave LDS RAW: drain DS writes, forbid compiler reordering
        asm volatile("s_waitcnt lgkmcnt(0)" ::: "memory");

        // ---- GEMM2 partial: out^T += W2^T @ h^T, K-chunk = 32 ----
        short8 hfr0 = *reinterpret_cast<const short8*>(hw + l16 * 80 + lg * 16);
        short8 hfr1 = *reinterpret_cast<const short8*>(hw + (16 + l16) * 80 + lg * 16);
        #pragma unroll
        for (int mt2 = 0; mt2 < 4; ++mt2) {
            short8 wf2 = *reinterpret_cast<const short8*>(
                w2a + (mt2 * 32 + hp * 4 + lg) * 128 + l16 * 8);
            acc2[mt2][0] = __builtin_amdgcn_mfma_f32_16x16x32_bf16(wf2, hfr0, acc2[mt2][0], 0, 0, 0);
            acc2[mt2][1] = __builtin_amdgcn_mfma_f32_16x16x32_bf16(wf2, hfr1, acc2[mt2][1], 0, 0, 0);
        }
        asm volatile("" ::: "memory");
    }

    // ---- epilogue: +b2, float4 nontemporal stores ----
    #pragma unroll
    for (int mt2 = 0; mt2 < 4; ++mt2) {
        float4 bb = *reinterpret_cast<const float4*>(b2 + mt2 * 16 + lg * 4);
        #pragma unroll
        for (int nf = 0; nf < 2; ++nf) {
            int e = ebase + nf * 16 + l16;
            f32x4 v;
            v[0] = acc2[mt2][nf][0] + bb.x;
            v[1] = acc2[mt2][nf][1] + bb.y;
            v[2] = acc2[mt2][nf][2] + bb.z;
            v[3] = acc2[mt2][nf][3] + bb.w;
            __builtin_nontemporal_store(v,
                reinterpret_cast<f32x4*>(outbuf + e * 64 + mt2 * 16 + lg * 4));
        }
    }
}

// ---- aggregate: one wave per node, lane = column, exact max over edge list ----
__global__ __launch_bounds__(256)
void agg_max(const unsigned* __restrict__ offs, const unsigned* __restrict__ elist,
             const float* __restrict__ outbuf, float* __restrict__ agg)
{
    const int wave = threadIdx.x >> 6, lane = threadIdx.x & 63;
    const int node = blockIdx.x * 4 + wave;
    if (node >= NNODES) return;
    const unsigned s = offs[node], eend = offs[node + 1];
    float m = -INFINITY;
    for (unsigned p = s; p < eend; ++p) {
        unsigned e = elist[p];
        m = fmaxf(m, outbuf[(size_t)e * 64 + lane]);
    }
    agg[(size_t)node * 64 + lane] = (s == eend) ? 0.0f : m;
}

extern "C" void kernel_launch(void* const* d_in, const int* in_sizes, int n_in,
                              void* d_out, int out_size, void* d_ws, size_t ws_size,
                              hipStream_t stream)
{
    const float* x  = (const float*)d_in[0];
    const int*   ei = (const int*)d_in[1];
    const float* ea = (const float*)d_in[2];
    const float* W1 = (const float*)d_in[3];
    const float* b1 = (const float*)d_in[4];
    const float* W2 = (const float*)d_in[5];
    const float* b2 = (const float*)d_in[6];

    float* aggp = (float*)d_out;                          // [N,64]
    float* outp = aggp + (size_t)NNODES * 64;             // [E,64]

    // ws layout (total ~3.92 MB, well under the proven-available 6.5 MB)
    short*    wpk  = (short*)d_ws;                        // 114,688 B packed W1+W2
    unsigned* meta = (unsigned*)((char*)d_ws + 114688);
    unsigned* cnt   = meta;                               // [50000]
    unsigned* cur   = meta + 50000;                       // [50000]
    unsigned* offs  = meta + 100000;                      // [50001]
    unsigned* bsum  = meta + 150016;                      // [49] (aligned)
    unsigned* elist = meta + 150144;                      // [800000]

    hipMemsetAsync(cnt, 0, 100000 * sizeof(unsigned), stream);   // cnt + cur
    prep_w<<<160, 256, 0, stream>>>(W1, W2, wpk);
    csr_count<<<NEDGES / 256, 256, 0, stream>>>(ei, cnt);
    csr_scan1<<<49, 1024, 0, stream>>>(cnt, offs, bsum);
    csr_scan2<<<1, 64, 0, stream>>>(bsum);
    csr_scan3<<<49, 1024, 0, stream>>>(cnt, offs, bsum);
    csr_place<<<NEDGES / 256, 256, 0, stream>>>(ei, offs, cur, elist);
    edgeconv_main<<<NEDGES / 128, 256, 0, stream>>>(x, ei, ea, wpk, b1, b2, outp);
    agg_max<<<(NNODES + 3) / 4, 256, 0, stream>>>(offs, elist, outp, aggp);
}

// Round 5
// 352.378 us; speedup vs baseline: 1.7944x; 1.7944x over previous
//
#include <hip/hip_runtime.h>
#include <math.h>

#define NNODES 50000
#define NEDGES 800000

using short8 = __attribute__((ext_vector_type(8))) short;   // 8 bf16 = 4 VGPRs
using f32x4  = __attribute__((ext_vector_type(4))) float;   // MFMA accumulator

// fp32 -> bf16 round-to-nearest-even
__device__ __forceinline__ short f2b(float v) {
    unsigned u = __builtin_bit_cast(unsigned, v);
    u = (u + 0x7FFFu + ((u >> 16) & 1u)) >> 16;
    return (short)u;
}

__device__ __forceinline__ unsigned pk2(short a, short b) {
    return (unsigned)(unsigned short)a | ((unsigned)(unsigned short)b << 16);
}

// ---- prep: x (fp32) -> xb (bf16) ----
__global__ void prep_x(const float* __restrict__ x, short* __restrict__ xb) {
    int i = blockIdx.x * 256 + threadIdx.x;          // over float4 groups
    if (i < NNODES * 64 / 4) {
        float4 v = reinterpret_cast<const float4*>(x)[i];
        short4 o;
        o.x = f2b(v.x); o.y = f2b(v.y); o.z = f2b(v.z); o.w = f2b(v.w);
        reinterpret_cast<short4*>(xb)[i] = o;
    }
}

// ---- prep: pack W1/W2 to bf16 fragment order (lane=non-K idx, 8 contiguous K) ----
__global__ void prep_w(const float* __restrict__ W1, const float* __restrict__ W2,
                       short* __restrict__ wpk) {
    int i = blockIdx.x * 256 + threadIdx.x;
    if (i < 40960) {            // W1 [k<160][n<256]
        int k = i >> 8, n = i & 255;
        wpk[((n >> 4) * 20 + (k >> 3)) * 128 + (n & 15) * 8 + (k & 7)] = f2b(W1[i]);
    }
    if (i < 16384) {            // W2 [k<256][n<64]
        int k = i >> 6, n = i & 63;
        wpk[40960 + ((n >> 4) * 32 + (k >> 3)) * 128 + (n & 15) * 8 + (k & 7)] = f2b(W2[i]);
    }
}

// ---- CSR build ----
__global__ void csr_count(const int* __restrict__ ei, unsigned* __restrict__ cnt) {
    int e = blockIdx.x * 256 + threadIdx.x;
    if (e < NEDGES) atomicAdd(&cnt[ei[e]], 1u);
}

// inclusive scan per 1024-block; block totals to bsum
__global__ __launch_bounds__(1024)
void csr_scan1(const unsigned* __restrict__ cnt, unsigned* __restrict__ offs,
               unsigned* __restrict__ bsum) {
    __shared__ unsigned sbuf[1024];
    int t = threadIdx.x, i = blockIdx.x * 1024 + t;
    unsigned v = (i < NNODES) ? cnt[i] : 0u;
    sbuf[t] = v;
    __syncthreads();
    for (int off = 1; off < 1024; off <<= 1) {
        unsigned add = (t >= off) ? sbuf[t - off] : 0u;
        __syncthreads();
        sbuf[t] += add;
        __syncthreads();
    }
    if (i < NNODES) offs[i] = sbuf[t];          // inclusive, fixed up in scan3
    if (t == 1023) bsum[blockIdx.x] = sbuf[1023];
}

// exclusive scan of the 49 block totals (single wave)
__global__ void csr_scan2(unsigned* __restrict__ bsum) {
    int t = threadIdx.x;
    unsigned v = (t < 49) ? bsum[t] : 0u;
    unsigned orig = v;
    for (int off = 1; off < 64; off <<= 1) {
        unsigned n = __shfl_up(v, off, 64);
        if (t >= off) v += n;
    }
    if (t < 49) bsum[t] = v - orig;             // exclusive
}

// inclusive -> exclusive + add block base; offs[NNODES] = NEDGES
__global__ __launch_bounds__(1024)
void csr_scan3(const unsigned* __restrict__ cnt, unsigned* __restrict__ offs,
               const unsigned* __restrict__ bsum) {
    int i = blockIdx.x * 1024 + threadIdx.x;
    if (i < NNODES)       offs[i] = offs[i] - cnt[i] + bsum[blockIdx.x];
    else if (i == NNODES) offs[i] = NEDGES;
}

__global__ void csr_place(const int* __restrict__ ei, const unsigned* __restrict__ offs,
                          unsigned* __restrict__ cur, unsigned* __restrict__ elist) {
    int e = blockIdx.x * 256 + threadIdx.x;
    if (e < NEDGES) {
        int r = ei[e];
        unsigned p = offs[r] + atomicAdd(&cur[r], 1u);
        elist[p] = (unsigned)e;
    }
}

// ---- main MLP: 4 waves/block, 32 edges/wave, bf16 gathers, no atomics ----
// launch_bounds(256,4): VGPR cap 128 >= ~110 live set -> no scratch spills.
__global__ __launch_bounds__(256, 4)
void edgeconv_main(const short* __restrict__ xb, const int* __restrict__ ei,
                   const float* __restrict__ ea, const short* __restrict__ wpk,
                   const float* __restrict__ b1, const float* __restrict__ b2,
                   float* __restrict__ outbuf)
{
    __shared__ char hbuf[4][32 * 80];   // 10,240 B: per-wave 32x32 h tile, 80-B stride

    const int tid  = threadIdx.x;
    const int wave = tid >> 6, lane = tid & 63;
    const int l16 = lane & 15, lg = lane >> 4;
    char* hw = hbuf[wave];
    const short* w2a = wpk + 40960;

    const int ebase = (blockIdx.x * 4 + wave) * 32;

    // ---- gather feats as GEMM1 B-fragments (col=edge=l16, k=lg*8..) ----
    short8 fx[2][5];
    #pragma unroll
    for (int nf = 0; nf < 2; ++nf) {
        int e = ebase + nf * 16 + l16;
        int r = ei[e], cc = ei[NEDGES + e];
        fx[nf][0] = *reinterpret_cast<const short8*>(xb + r * 64 + lg * 8);
        fx[nf][1] = *reinterpret_cast<const short8*>(xb + r * 64 + 32 + lg * 8);
        fx[nf][2] = *reinterpret_cast<const short8*>(xb + cc * 64 + lg * 8);
        fx[nf][3] = *reinterpret_cast<const short8*>(xb + cc * 64 + 32 + lg * 8);
        const float4* eap = reinterpret_cast<const float4*>(ea + e * 32 + lg * 8);
        float4 va = eap[0], vb = eap[1];
        short8 f;
        f[0]=f2b(va.x); f[1]=f2b(va.y); f[2]=f2b(va.z); f[3]=f2b(va.w);
        f[4]=f2b(vb.x); f[5]=f2b(vb.y); f[6]=f2b(vb.z); f[7]=f2b(vb.w);
        fx[nf][4] = f;
    }

    f32x4 acc2[4][2] = {};   // [outcol-tile mt2][edge-tile nf]

    #pragma unroll 1
    for (int hp = 0; hp < 8; ++hp) {     // 8 phases of 32 H-cols
        // ---- GEMM1: h^T tile = W1^T @ feats^T (weight frags from L1/L2) ----
        f32x4 acc1[2][2] = {};
        #pragma unroll
        for (int kk = 0; kk < 5; ++kk) {
            #pragma unroll
            for (int mt = 0; mt < 2; ++mt) {
                int nt = hp * 2 + mt;
                short8 wf = *reinterpret_cast<const short8*>(
                    wpk + (nt * 20 + kk * 4 + lg) * 128 + l16 * 8);
                acc1[mt][0] = __builtin_amdgcn_mfma_f32_16x16x32_bf16(wf, fx[0][kk], acc1[mt][0], 0, 0, 0);
                acc1[mt][1] = __builtin_amdgcn_mfma_f32_16x16x32_bf16(wf, fx[1][kk], acc1[mt][1], 0, 0, 0);
            }
        }
        // ---- bias + ReLU + pack: 8-B LDS writes, h[edge][hcol] k-contiguous ----
        #pragma unroll
        for (int mt = 0; mt < 2; ++mt) {
            float4 bb = *reinterpret_cast<const float4*>(b1 + hp * 32 + mt * 16 + lg * 4);
            #pragma unroll
            for (int nf = 0; nf < 2; ++nf) {
                float v0 = fmaxf(acc1[mt][nf][0] + bb.x, 0.0f);
                float v1 = fmaxf(acc1[mt][nf][1] + bb.y, 0.0f);
                float v2 = fmaxf(acc1[mt][nf][2] + bb.z, 0.0f);
                float v3 = fmaxf(acc1[mt][nf][3] + bb.w, 0.0f);
                unsigned long long p =
                    (unsigned long long)pk2(f2b(v0), f2b(v1)) |
                    ((unsigned long long)pk2(f2b(v2), f2b(v3)) << 32);
                *reinterpret_cast<unsigned long long*>(
                    hw + (nf * 16 + l16) * 80 + mt * 32 + lg * 8) = p;
            }
        }
        // in-wave LDS RAW: DS pipe is in-order per wave; clobber stops reordering
        asm volatile("s_waitcnt lgkmcnt(0)" ::: "memory");

        // ---- GEMM2 partial: out^T += W2^T @ h^T, K-chunk = 32 ----
        short8 hfr0 = *reinterpret_cast<const short8*>(hw + l16 * 80 + lg * 16);
        short8 hfr1 = *reinterpret_cast<const short8*>(hw + (16 + l16) * 80 + lg * 16);
        #pragma unroll
        for (int mt2 = 0; mt2 < 4; ++mt2) {
            short8 wf2 = *reinterpret_cast<const short8*>(
                w2a + (mt2 * 32 + hp * 4 + lg) * 128 + l16 * 8);
            acc2[mt2][0] = __builtin_amdgcn_mfma_f32_16x16x32_bf16(wf2, hfr0, acc2[mt2][0], 0, 0, 0);
            acc2[mt2][1] = __builtin_amdgcn_mfma_f32_16x16x32_bf16(wf2, hfr1, acc2[mt2][1], 0, 0, 0);
        }
        asm volatile("" ::: "memory");
    }

    // ---- epilogue: +b2, float4 nontemporal stores ----
    #pragma unroll
    for (int mt2 = 0; mt2 < 4; ++mt2) {
        float4 bb = *reinterpret_cast<const float4*>(b2 + mt2 * 16 + lg * 4);
        #pragma unroll
        for (int nf = 0; nf < 2; ++nf) {
            int e = ebase + nf * 16 + l16;
            f32x4 v;
            v[0] = acc2[mt2][nf][0] + bb.x;
            v[1] = acc2[mt2][nf][1] + bb.y;
            v[2] = acc2[mt2][nf][2] + bb.z;
            v[3] = acc2[mt2][nf][3] + bb.w;
            __builtin_nontemporal_store(v,
                reinterpret_cast<f32x4*>(outbuf + e * 64 + mt2 * 16 + lg * 4));
        }
    }
}

// ---- aggregate: one wave per node, lane = column, exact max over edge list ----
__global__ __launch_bounds__(256)
void agg_max(const unsigned* __restrict__ offs, const unsigned* __restrict__ elist,
             const float* __restrict__ outbuf, float* __restrict__ agg)
{
    const int wave = threadIdx.x >> 6, lane = threadIdx.x & 63;
    const int node = blockIdx.x * 4 + wave;
    if (node >= NNODES) return;
    const unsigned s = offs[node], eend = offs[node + 1];
    float m = -INFINITY;
    for (unsigned p = s; p < eend; ++p) {
        unsigned e = elist[p];
        m = fmaxf(m, outbuf[(size_t)e * 64 + lane]);
    }
    agg[(size_t)node * 64 + lane] = (s == eend) ? 0.0f : m;
}

extern "C" void kernel_launch(void* const* d_in, const int* in_sizes, int n_in,
                              void* d_out, int out_size, void* d_ws, size_t ws_size,
                              hipStream_t stream)
{
    const float* x  = (const float*)d_in[0];
    const int*   ei = (const int*)d_in[1];
    const float* ea = (const float*)d_in[2];
    const float* W1 = (const float*)d_in[3];
    const float* b1 = (const float*)d_in[4];
    const float* W2 = (const float*)d_in[5];
    const float* b2 = (const float*)d_in[6];

    float* aggp = (float*)d_out;                          // [N,64]
    float* outp = aggp + (size_t)NNODES * 64;             // [E,64]

    // ws layout (~10.3 MB total)
    short*    xb   = (short*)d_ws;                        // 6,400,000 B bf16 x
    short*    wpk  = (short*)((char*)d_ws + 6400000);     //   114,688 B packed W1+W2
    unsigned* meta = (unsigned*)((char*)d_ws + 6514688);
    unsigned* cnt   = meta;                               // [50000]
    unsigned* cur   = meta + 50000;                       // [50000]
    unsigned* offs  = meta + 100000;                      // [50001]
    unsigned* bsum  = meta + 150016;                      // [49] (aligned)
    unsigned* elist = meta + 150144;                      // [800000]

    hipMemsetAsync(cnt, 0, 100000 * sizeof(unsigned), stream);   // cnt + cur
    prep_x<<<NNODES * 64 / 4 / 256, 256, 0, stream>>>(x, xb);
    prep_w<<<160, 256, 0, stream>>>(W1, W2, wpk);
    csr_count<<<NEDGES / 256, 256, 0, stream>>>(ei, cnt);
    csr_scan1<<<49, 1024, 0, stream>>>(cnt, offs, bsum);
    csr_scan2<<<1, 64, 0, stream>>>(bsum);
    csr_scan3<<<49, 1024, 0, stream>>>(cnt, offs, bsum);
    csr_place<<<NEDGES / 256, 256, 0, stream>>>(ei, offs, cur, elist);
    edgeconv_main<<<NEDGES / 128, 256, 0, stream>>>(xb, ei, ea, wpk, b1, b2, outp);
    agg_max<<<(NNODES + 3) / 4, 256, 0, stream>>>(offs, elist, outp, aggp);
}

// Round 6
// 327.199 us; speedup vs baseline: 1.9324x; 1.0770x over previous
//
#include <hip/hip_runtime.h>
#include <hip/hip_bf16.h>
#include <math.h>

#define NNODES 50000
#define NEDGES 800000
#define CHUNKS (NEDGES / 32)     // 25000 chunks of 32 edges
#define GWAVES 4096              // 256 blocks x 16 waves

using short8 = __attribute__((ext_vector_type(8))) short;   // 8 bf16 = 4 VGPRs
using f32x4  = __attribute__((ext_vector_type(4))) float;   // MFMA accumulator

// fp32 -> bf16 RNE via native cvt (compiler fuses pairs into v_cvt_pk_bf16_f32)
__device__ __forceinline__ short f2b(float v) {
    return __builtin_bit_cast(short, __float2bfloat16(v));
}

__device__ __forceinline__ unsigned pk2(short a, short b) {
    return (unsigned)(unsigned short)a | ((unsigned)(unsigned short)b << 16);
}

// ---- prep: x (fp32) -> xb (bf16) ----
__global__ void prep_x(const float* __restrict__ x, short* __restrict__ xb) {
    int i = blockIdx.x * 256 + threadIdx.x;          // over float4 groups
    if (i < NNODES * 64 / 4) {
        float4 v = reinterpret_cast<const float4*>(x)[i];
        short4 o;
        o.x = f2b(v.x); o.y = f2b(v.y); o.z = f2b(v.z); o.w = f2b(v.w);
        reinterpret_cast<short4*>(xb)[i] = o;
    }
}

// ---- prep: pack W1/W2 to bf16 fragment order (lane=non-K idx, 8 contiguous K) ----
__global__ void prep_w(const float* __restrict__ W1, const float* __restrict__ W2,
                       short* __restrict__ wpk) {
    int i = blockIdx.x * 256 + threadIdx.x;
    if (i < 40960) {            // W1 [k<160][n<256]
        int k = i >> 8, n = i & 255;
        wpk[((n >> 4) * 20 + (k >> 3)) * 128 + (n & 15) * 8 + (k & 7)] = f2b(W1[i]);
    }
    if (i < 16384) {            // W2 [k<256][n<64]
        int k = i >> 6, n = i & 63;
        wpk[40960 + ((n >> 4) * 32 + (k >> 3)) * 128 + (n & 15) * 8 + (k & 7)] = f2b(W2[i]);
    }
}

// ---- CSR build ----
__global__ void csr_count(const int* __restrict__ ei, unsigned* __restrict__ cnt) {
    int e = blockIdx.x * 256 + threadIdx.x;
    if (e < NEDGES) atomicAdd(&cnt[ei[e]], 1u);
}

__global__ __launch_bounds__(1024)
void csr_scan1(const unsigned* __restrict__ cnt, unsigned* __restrict__ offs,
               unsigned* __restrict__ bsum) {
    __shared__ unsigned sbuf[1024];
    int t = threadIdx.x, i = blockIdx.x * 1024 + t;
    unsigned v = (i < NNODES) ? cnt[i] : 0u;
    sbuf[t] = v;
    __syncthreads();
    for (int off = 1; off < 1024; off <<= 1) {
        unsigned add = (t >= off) ? sbuf[t - off] : 0u;
        __syncthreads();
        sbuf[t] += add;
        __syncthreads();
    }
    if (i < NNODES) offs[i] = sbuf[t];          // inclusive, fixed up in scan3
    if (t == 1023) bsum[blockIdx.x] = sbuf[1023];
}

__global__ void csr_scan2(unsigned* __restrict__ bsum) {
    int t = threadIdx.x;
    unsigned v = (t < 49) ? bsum[t] : 0u;
    unsigned orig = v;
    for (int off = 1; off < 64; off <<= 1) {
        unsigned n = __shfl_up(v, off, 64);
        if (t >= off) v += n;
    }
    if (t < 49) bsum[t] = v - orig;             // exclusive
}

__global__ __launch_bounds__(1024)
void csr_scan3(const unsigned* __restrict__ cnt, unsigned* __restrict__ offs,
               const unsigned* __restrict__ bsum) {
    int i = blockIdx.x * 1024 + threadIdx.x;
    if (i < NNODES)       offs[i] = offs[i] - cnt[i] + bsum[blockIdx.x];
    else if (i == NNODES) offs[i] = NEDGES;
}

__global__ void csr_place(const int* __restrict__ ei, const unsigned* __restrict__ offs,
                          unsigned* __restrict__ cur, unsigned* __restrict__ elist) {
    int e = blockIdx.x * 256 + threadIdx.x;
    if (e < NEDGES) {
        int r = ei[e];
        unsigned p = offs[r] + atomicAdd(&cur[r], 1u);
        elist[p] = (unsigned)e;
    }
}

// ---- main MLP: persistent, 16 waves/block, weights in LDS, bias in C-init ----
__global__ __launch_bounds__(1024, 4)
void edgeconv_main(const short* __restrict__ xb, const int* __restrict__ ei,
                   const float* __restrict__ ea, const short* __restrict__ wpk,
                   const float* __restrict__ b1, const float* __restrict__ b2,
                   float* __restrict__ outbuf)
{
    __shared__ short wlds[57344];        // 112 KB: packed W1 (80K) + W2 (32K)
    __shared__ char  hbuf[16][2560];     //  40 KB: per-wave 32x32 h tile, 80-B stride

    const int tid = threadIdx.x;
    // stage all weights once per CU (contiguous 16-B copies)
    for (int i = tid; i < 7168; i += 1024)
        reinterpret_cast<short8*>(wlds)[i] = reinterpret_cast<const short8*>(wpk)[i];
    __syncthreads();                     // only block-wide barrier

    const short* w1s = wlds;
    const short* w2s = wlds + 40960;
    const int wave = tid >> 6, lane = tid & 63;
    const int l16 = lane & 15, lg = lane >> 4;
    char* hw = hbuf[wave];
    const int gw = blockIdx.x * 16 + wave;

    for (int c = gw; c < CHUNKS; c += GWAVES) {
        const int ebase = c * 32;

        // ---- gather feats as GEMM1 B-fragments (col=edge=l16, k=lg*8..) ----
        short8 fx[2][5];
        #pragma unroll
        for (int nf = 0; nf < 2; ++nf) {
            int e = ebase + nf * 16 + l16;
            int r = ei[e], cc = ei[NEDGES + e];
            fx[nf][0] = *reinterpret_cast<const short8*>(xb + r * 64 + lg * 8);
            fx[nf][1] = *reinterpret_cast<const short8*>(xb + r * 64 + 32 + lg * 8);
            fx[nf][2] = *reinterpret_cast<const short8*>(xb + cc * 64 + lg * 8);
            fx[nf][3] = *reinterpret_cast<const short8*>(xb + cc * 64 + 32 + lg * 8);
            const float4* eap = reinterpret_cast<const float4*>(ea + e * 32 + lg * 8);
            float4 va = eap[0], vb = eap[1];
            short8 f;
            f[0]=f2b(va.x); f[1]=f2b(va.y); f[2]=f2b(va.z); f[3]=f2b(va.w);
            f[4]=f2b(vb.x); f[5]=f2b(vb.y); f[6]=f2b(vb.z); f[7]=f2b(vb.w);
            fx[nf][4] = f;
        }

        // ---- acc2 init = b2 broadcast (bias folded into C) ----
        f32x4 acc2[4][2];
        #pragma unroll
        for (int mt2 = 0; mt2 < 4; ++mt2) {
            float4 bb = *reinterpret_cast<const float4*>(b2 + mt2 * 16 + lg * 4);
            f32x4 bi; bi[0] = bb.x; bi[1] = bb.y; bi[2] = bb.z; bi[3] = bb.w;
            acc2[mt2][0] = bi; acc2[mt2][1] = bi;
        }

        #pragma unroll 1
        for (int hp = 0; hp < 8; ++hp) {     // 8 phases of 32 H-cols
            // ---- GEMM1: h^T tile = W1^T @ feats^T, C-init = b1 ----
            f32x4 acc1[2][2];
            #pragma unroll
            for (int mt = 0; mt < 2; ++mt) {
                float4 bb = *reinterpret_cast<const float4*>(b1 + hp * 32 + mt * 16 + lg * 4);
                f32x4 bi; bi[0] = bb.x; bi[1] = bb.y; bi[2] = bb.z; bi[3] = bb.w;
                acc1[mt][0] = bi; acc1[mt][1] = bi;
            }
            #pragma unroll
            for (int kk = 0; kk < 5; ++kk) {
                #pragma unroll
                for (int mt = 0; mt < 2; ++mt) {
                    int nt = hp * 2 + mt;
                    short8 wf = *reinterpret_cast<const short8*>(
                        w1s + (nt * 20 + kk * 4 + lg) * 128 + l16 * 8);
                    acc1[mt][0] = __builtin_amdgcn_mfma_f32_16x16x32_bf16(wf, fx[0][kk], acc1[mt][0], 0, 0, 0);
                    acc1[mt][1] = __builtin_amdgcn_mfma_f32_16x16x32_bf16(wf, fx[1][kk], acc1[mt][1], 0, 0, 0);
                }
            }
            // ---- ReLU + pack: 8-B LDS writes, h[edge][hcol] k-contiguous ----
            #pragma unroll
            for (int mt = 0; mt < 2; ++mt) {
                #pragma unroll
                for (int nf = 0; nf < 2; ++nf) {
                    float v0 = fmaxf(acc1[mt][nf][0], 0.0f);
                    float v1 = fmaxf(acc1[mt][nf][1], 0.0f);
                    float v2 = fmaxf(acc1[mt][nf][2], 0.0f);
                    float v3 = fmaxf(acc1[mt][nf][3], 0.0f);
                    unsigned long long p =
                        (unsigned long long)pk2(f2b(v0), f2b(v1)) |
                        ((unsigned long long)pk2(f2b(v2), f2b(v3)) << 32);
                    *reinterpret_cast<unsigned long long*>(
                        hw + (nf * 16 + l16) * 80 + mt * 32 + lg * 8) = p;
                }
            }
            // in-wave LDS RAW: drain DS writes; clobber stops reordering
            asm volatile("s_waitcnt lgkmcnt(0)" ::: "memory");

            // ---- GEMM2 partial: out^T += W2^T @ h^T, K-chunk = 32 ----
            short8 hfr0 = *reinterpret_cast<const short8*>(hw + l16 * 80 + lg * 16);
            short8 hfr1 = *reinterpret_cast<const short8*>(hw + (16 + l16) * 80 + lg * 16);
            #pragma unroll
            for (int mt2 = 0; mt2 < 4; ++mt2) {
                short8 wf2 = *reinterpret_cast<const short8*>(
                    w2s + (mt2 * 32 + hp * 4 + lg) * 128 + l16 * 8);
                acc2[mt2][0] = __builtin_amdgcn_mfma_f32_16x16x32_bf16(wf2, hfr0, acc2[mt2][0], 0, 0, 0);
                acc2[mt2][1] = __builtin_amdgcn_mfma_f32_16x16x32_bf16(wf2, hfr1, acc2[mt2][1], 0, 0, 0);
            }
            asm volatile("" ::: "memory");
        }

        // ---- epilogue: float4 nontemporal stores (bias already in acc) ----
        #pragma unroll
        for (int mt2 = 0; mt2 < 4; ++mt2) {
            #pragma unroll
            for (int nf = 0; nf < 2; ++nf) {
                int e = ebase + nf * 16 + l16;
                __builtin_nontemporal_store(acc2[mt2][nf],
                    reinterpret_cast<f32x4*>(outbuf + e * 64 + mt2 * 16 + lg * 4));
            }
        }
    }
}

// ---- aggregate: one wave per node, lane = column, 2-deep ILP max walk ----
__global__ __launch_bounds__(256)
void agg_max(const unsigned* __restrict__ offs, const unsigned* __restrict__ elist,
             const float* __restrict__ outbuf, float* __restrict__ agg)
{
    const int wave = threadIdx.x >> 6, lane = threadIdx.x & 63;
    const int node = blockIdx.x * 4 + wave;
    if (node >= NNODES) return;
    const unsigned s = offs[node], eend = offs[node + 1];
    float m0 = -INFINITY, m1 = -INFINITY;
    unsigned p = s;
    for (; p + 2 <= eend; p += 2) {
        unsigned e0 = elist[p], e1 = elist[p + 1];
        float a = outbuf[(size_t)e0 * 64 + lane];
        float b = outbuf[(size_t)e1 * 64 + lane];
        m0 = fmaxf(m0, a);
        m1 = fmaxf(m1, b);
    }
    if (p < eend) m0 = fmaxf(m0, outbuf[(size_t)elist[p] * 64 + lane]);
    float m = fmaxf(m0, m1);
    agg[(size_t)node * 64 + lane] = (s == eend) ? 0.0f : m;
}

extern "C" void kernel_launch(void* const* d_in, const int* in_sizes, int n_in,
                              void* d_out, int out_size, void* d_ws, size_t ws_size,
                              hipStream_t stream)
{
    const float* x  = (const float*)d_in[0];
    const int*   ei = (const int*)d_in[1];
    const float* ea = (const float*)d_in[2];
    const float* W1 = (const float*)d_in[3];
    const float* b1 = (const float*)d_in[4];
    const float* W2 = (const float*)d_in[5];
    const float* b2 = (const float*)d_in[6];

    float* aggp = (float*)d_out;                          // [N,64]
    float* outp = aggp + (size_t)NNODES * 64;             // [E,64]

    // ws layout (~10.3 MB total)
    short*    xb   = (short*)d_ws;                        // 6,400,000 B bf16 x
    short*    wpk  = (short*)((char*)d_ws + 6400000);     //   114,688 B packed W1+W2
    unsigned* meta = (unsigned*)((char*)d_ws + 6514688);
    unsigned* cnt   = meta;                               // [50000]
    unsigned* cur   = meta + 50000;                       // [50000]
    unsigned* offs  = meta + 100000;                      // [50001]
    unsigned* bsum  = meta + 150016;                      // [49] (aligned)
    unsigned* elist = meta + 150144;                      // [800000]

    hipMemsetAsync(cnt, 0, 100000 * sizeof(unsigned), stream);   // cnt + cur
    prep_x<<<NNODES * 64 / 4 / 256, 256, 0, stream>>>(x, xb);
    prep_w<<<160, 256, 0, stream>>>(W1, W2, wpk);
    csr_count<<<NEDGES / 256, 256, 0, stream>>>(ei, cnt);
    csr_scan1<<<49, 1024, 0, stream>>>(cnt, offs, bsum);
    csr_scan2<<<1, 64, 0, stream>>>(bsum);
    csr_scan3<<<49, 1024, 0, stream>>>(cnt, offs, bsum);
    csr_place<<<NEDGES / 256, 256, 0, stream>>>(ei, offs, cur, elist);
    edgeconv_main<<<256, 1024, 0, stream>>>(xb, ei, ea, wpk, b1, b2, outp);
    agg_max<<<(NNODES + 3) / 4, 256, 0, stream>>>(offs, elist, outp, aggp);
}

// Round 8
// 300.830 us; speedup vs baseline: 2.1018x; 1.0877x over previous
//
#include <hip/hip_runtime.h>
#include <hip/hip_bf16.h>
#include <math.h>

#define NNODES 50000
#define NEDGES 800000
#define CHUNKS (NEDGES / 32)     // 25000 chunks of 32 edges
#define NBLK 256
#define GWAVES (NBLK * 16)       // persistent waves

using short8 = __attribute__((ext_vector_type(8))) short;   // 8 bf16 = 4 VGPRs
using f32x4  = __attribute__((ext_vector_type(4))) float;
using f32x16 = __attribute__((ext_vector_type(16))) float;  // 32x32 MFMA acc
using u32x4  = __attribute__((ext_vector_type(4))) unsigned;

// fp32 -> bf16 RNE
__device__ __forceinline__ short f2b(float v) {
    return __builtin_bit_cast(short, __float2bfloat16(v));
}
// pack 2 fp32 -> 1 dword of 2 bf16 (lo = a); trivially-copyable path,
// compiler fuses to v_cvt_pk_bf16_f32 where profitable
__device__ __forceinline__ unsigned cvt2(float a, float b) {
    return (unsigned)(unsigned short)f2b(a) | ((unsigned)(unsigned short)f2b(b) << 16);
}

// ---- merged prep: x->bf16, W pack, CSR count (independent, one launch) ----
// W packing for 32x32x16 A-fragments: A row = lane&31 (out-col of W^T),
// k = (lane>>5)*8 + j, j = k&7 contiguous. One fragment = 64 lanes x 16 B.
__global__ void prep_all(const float* __restrict__ x, short* __restrict__ xb,
                         const float* __restrict__ W1, const float* __restrict__ W2,
                         short* __restrict__ wpk, const int* __restrict__ ei,
                         unsigned* __restrict__ cnt)
{
    int b = blockIdx.x;
    if (b < 3125) {                       // x -> bf16 (800000 float4 groups)
        int i = b * 256 + threadIdx.x;
        float4 v = reinterpret_cast<const float4*>(x)[i];
        short4 o;
        o.x = f2b(v.x); o.y = f2b(v.y); o.z = f2b(v.z); o.w = f2b(v.w);
        reinterpret_cast<short4*>(xb)[i] = o;
    } else if (b < 6250) {                // CSR degree count
        int e = (b - 3125) * 256 + threadIdx.x;
        atomicAdd(&cnt[ei[e]], 1u);
    } else {                              // weight pack
        int i = (b - 6250) * 256 + threadIdx.x;
        if (i < 40960) {                  // W1 [k<160][n<256]
            int k = i >> 8, n = i & 255;
            int lane = (n & 31) + (((k >> 3) & 1) << 5);
            wpk[(((n >> 5) * 10 + (k >> 4)) * 64 + lane) * 8 + (k & 7)] = f2b(W1[i]);
        }
        if (i < 16384) {                  // W2 [k<256][n<64]
            int k = i >> 6, n = i & 63;
            int lane = (n & 31) + (((k >> 3) & 1) << 5);
            wpk[40960 + (((n >> 5) * 16 + (k >> 4)) * 64 + lane) * 8 + (k & 7)] = f2b(W2[i]);
        }
    }
}

// ---- CSR scan/place (unchanged, proven) ----
__global__ __launch_bounds__(1024)
void csr_scan1(const unsigned* __restrict__ cnt, unsigned* __restrict__ offs,
               unsigned* __restrict__ bsum) {
    __shared__ unsigned sbuf[1024];
    int t = threadIdx.x, i = blockIdx.x * 1024 + t;
    unsigned v = (i < NNODES) ? cnt[i] : 0u;
    sbuf[t] = v;
    __syncthreads();
    for (int off = 1; off < 1024; off <<= 1) {
        unsigned add = (t >= off) ? sbuf[t - off] : 0u;
        __syncthreads();
        sbuf[t] += add;
        __syncthreads();
    }
    if (i < NNODES) offs[i] = sbuf[t];
    if (t == 1023) bsum[blockIdx.x] = sbuf[1023];
}

__global__ void csr_scan2(unsigned* __restrict__ bsum) {
    int t = threadIdx.x;
    unsigned v = (t < 49) ? bsum[t] : 0u;
    unsigned orig = v;
    for (int off = 1; off < 64; off <<= 1) {
        unsigned n = __shfl_up(v, off, 64);
        if (t >= off) v += n;
    }
    if (t < 49) bsum[t] = v - orig;
}

__global__ __launch_bounds__(1024)
void csr_scan3(const unsigned* __restrict__ cnt, unsigned* __restrict__ offs,
               const unsigned* __restrict__ bsum) {
    int i = blockIdx.x * 1024 + threadIdx.x;
    if (i < NNODES)       offs[i] = offs[i] - cnt[i] + bsum[blockIdx.x];
    else if (i == NNODES) offs[i] = NEDGES;
}

__global__ void csr_place(const int* __restrict__ ei, const unsigned* __restrict__ offs,
                          unsigned* __restrict__ cur, unsigned* __restrict__ elist) {
    int e = blockIdx.x * 256 + threadIdx.x;
    if (e < NEDGES) {
        int r = ei[e];
        unsigned p = offs[r] + atomicAdd(&cur[r], 1u);
        elist[p] = (unsigned)e;
    }
}

// ---- main MLP: 32x32x16 MFMA, no h LDS round-trip (permlane32_swap) ----
__global__ __launch_bounds__(1024, 4)
void edgeconv_main(const short* __restrict__ xb, const int* __restrict__ ei,
                   const float* __restrict__ ea, const short* __restrict__ wpk,
                   const float* __restrict__ b1, const float* __restrict__ b2,
                   float* __restrict__ outbuf)
{
    __shared__ short wlds[57344];        // 112 KB: W1 frags (80K) + W2 frags (32K)

    for (int i = threadIdx.x; i < 7168; i += 1024)
        reinterpret_cast<short8*>(wlds)[i] = reinterpret_cast<const short8*>(wpk)[i];
    __syncthreads();                     // only block-wide barrier

    const short* w1s = wlds;
    const short* w2s = wlds + 40960;
    const int lane = threadIdx.x & 63;
    const int wave = threadIdx.x >> 6;
    const int l32 = lane & 31, hi = lane >> 5;
    const int gw = blockIdx.x * 16 + wave;

    for (int c = gw; c < CHUNKS; c += GWAVES) {
        const int ebase = c * 32;
        const int e = ebase + l32;       // one edge per lane (col of B-frag)
        const int r = ei[e], cc = ei[NEDGES + e];

        // ---- gather B-fragments: k = ks*16 + hi*8 + j ----
        short8 fx[10];
        #pragma unroll
        for (int ks = 0; ks < 4; ++ks)
            fx[ks] = *reinterpret_cast<const short8*>(xb + r * 64 + ks * 16 + hi * 8);
        #pragma unroll
        for (int ks = 0; ks < 4; ++ks)
            fx[4 + ks] = *reinterpret_cast<const short8*>(xb + cc * 64 + ks * 16 + hi * 8);
        #pragma unroll
        for (int ks = 0; ks < 2; ++ks) {
            const float4* p = reinterpret_cast<const float4*>(ea + e * 32 + ks * 16 + hi * 8);
            float4 a = p[0], b = p[1];
            u32x4 uu;
            uu[0] = cvt2(a.x, a.y); uu[1] = cvt2(a.z, a.w);
            uu[2] = cvt2(b.x, b.y); uu[3] = cvt2(b.z, b.w);
            fx[8 + ks] = __builtin_bit_cast(short8, uu);
        }

        // ---- acc2 init = b2 (D row m = (q&3)+8*(q>>2)+4*hi = out-col) ----
        f32x16 acc2[2];
        #pragma unroll
        for (int t2 = 0; t2 < 2; ++t2)
            #pragma unroll
            for (int g = 0; g < 4; ++g) {
                float4 bb = *reinterpret_cast<const float4*>(b2 + t2 * 32 + g * 8 + hi * 4);
                acc2[t2][g * 4 + 0] = bb.x; acc2[t2][g * 4 + 1] = bb.y;
                acc2[t2][g * 4 + 2] = bb.z; acc2[t2][g * 4 + 3] = bb.w;
            }

        #pragma unroll 1
        for (int t = 0; t < 8; ++t) {    // 8 H-tiles of 32 cols
            // ---- GEMM1: h^T(32xH tile) = W1^T @ feats^T, C-init = b1 ----
            f32x16 acc1;
            #pragma unroll
            for (int g = 0; g < 4; ++g) {
                float4 bb = *reinterpret_cast<const float4*>(b1 + t * 32 + g * 8 + hi * 4);
                acc1[g * 4 + 0] = bb.x; acc1[g * 4 + 1] = bb.y;
                acc1[g * 4 + 2] = bb.z; acc1[g * 4 + 3] = bb.w;
            }
            #pragma unroll
            for (int ks = 0; ks < 10; ++ks) {
                short8 wf = *reinterpret_cast<const short8*>(
                    w1s + ((t * 10 + ks) * 64 + lane) * 8);
                acc1 = __builtin_amdgcn_mfma_f32_32x32x16_bf16(wf, fx[ks], acc1, 0, 0, 0);
            }
            // ---- ReLU + bf16 + permlane32_swap -> GEMM2 B-frags in-register ----
            #pragma unroll
            for (int ksl = 0; ksl < 2; ++ksl) {
                int q0 = ksl * 8;
                unsigned D0 = cvt2(fmaxf(acc1[q0 + 0], 0.f), fmaxf(acc1[q0 + 1], 0.f));
                unsigned D1 = cvt2(fmaxf(acc1[q0 + 2], 0.f), fmaxf(acc1[q0 + 3], 0.f));
                unsigned D2 = cvt2(fmaxf(acc1[q0 + 4], 0.f), fmaxf(acc1[q0 + 5], 0.f));
                unsigned D3 = cvt2(fmaxf(acc1[q0 + 6], 0.f), fmaxf(acc1[q0 + 7], 0.f));
                // a.hi <-> b.lo : delivers the cross-half H values each lane needs
                asm volatile("v_permlane32_swap_b32 %0, %1" : "+v"(D0), "+v"(D2));
                asm volatile("v_permlane32_swap_b32 %0, %1" : "+v"(D1), "+v"(D3));
                u32x4 bu; bu[0] = D0; bu[1] = D1; bu[2] = D2; bu[3] = D3;
                short8 hb = __builtin_bit_cast(short8, bu);

                int ks2 = t * 2 + ksl;   // global GEMM2 k-step (0..15)
                short8 w20 = *reinterpret_cast<const short8*>(w2s + (ks2 * 64 + lane) * 8);
                short8 w21 = *reinterpret_cast<const short8*>(w2s + ((16 + ks2) * 64 + lane) * 8);
                acc2[0] = __builtin_amdgcn_mfma_f32_32x32x16_bf16(w20, hb, acc2[0], 0, 0, 0);
                acc2[1] = __builtin_amdgcn_mfma_f32_32x32x16_bf16(w21, hb, acc2[1], 0, 0, 0);
            }
        }

        // ---- epilogue: float4 stores (normal: keep out L3-resident for agg) ----
        #pragma unroll
        for (int t2 = 0; t2 < 2; ++t2)
            #pragma unroll
            for (int g = 0; g < 4; ++g) {
                f32x4 v;
                v[0] = acc2[t2][g * 4 + 0]; v[1] = acc2[t2][g * 4 + 1];
                v[2] = acc2[t2][g * 4 + 2]; v[3] = acc2[t2][g * 4 + 3];
                *reinterpret_cast<f32x4*>(outbuf + (size_t)e * 64 + t2 * 32 + g * 8 + hi * 4) = v;
            }
    }
}

// ---- aggregate: one wave per node, lane = column, 4-deep ILP max walk ----
__global__ __launch_bounds__(256)
void agg_max(const unsigned* __restrict__ offs, const unsigned* __restrict__ elist,
             const float* __restrict__ outbuf, float* __restrict__ agg)
{
    const int wave = threadIdx.x >> 6, lane = threadIdx.x & 63;
    const int node = blockIdx.x * 4 + wave;
    if (node >= NNODES) return;
    const unsigned s = offs[node], eend = offs[node + 1];
    float m0 = -INFINITY, m1 = -INFINITY, m2 = -INFINITY, m3 = -INFINITY;
    unsigned p = s;
    for (; p + 4 <= eend; p += 4) {
        float a = outbuf[(size_t)elist[p + 0] * 64 + lane];
        float b = outbuf[(size_t)elist[p + 1] * 64 + lane];
        float c = outbuf[(size_t)elist[p + 2] * 64 + lane];
        float d = outbuf[(size_t)elist[p + 3] * 64 + lane];
        m0 = fmaxf(m0, a); m1 = fmaxf(m1, b);
        m2 = fmaxf(m2, c); m3 = fmaxf(m3, d);
    }
    for (; p < eend; ++p) m0 = fmaxf(m0, outbuf[(size_t)elist[p] * 64 + lane]);
    float m = fmaxf(fmaxf(m0, m1), fmaxf(m2, m3));
    agg[(size_t)node * 64 + lane] = (s == eend) ? 0.0f : m;
}

extern "C" void kernel_launch(void* const* d_in, const int* in_sizes, int n_in,
                              void* d_out, int out_size, void* d_ws, size_t ws_size,
                              hipStream_t stream)
{
    const float* x  = (const float*)d_in[0];
    const int*   ei = (const int*)d_in[1];
    const float* ea = (const float*)d_in[2];
    const float* W1 = (const float*)d_in[3];
    const float* b1 = (const float*)d_in[4];
    const float* W2 = (const float*)d_in[5];
    const float* b2 = (const float*)d_in[6];

    float* aggp = (float*)d_out;                          // [N,64]
    float* outp = aggp + (size_t)NNODES * 64;             // [E,64]

    // ws layout (~10.3 MB)
    short*    xb   = (short*)d_ws;                        // 6,400,000 B bf16 x
    short*    wpk  = (short*)((char*)d_ws + 6400000);     //   114,688 B packed W1+W2
    unsigned* meta = (unsigned*)((char*)d_ws + 6514688);
    unsigned* cnt   = meta;                               // [50000]
    unsigned* cur   = meta + 50000;                       // [50000]
    unsigned* offs  = meta + 100000;                      // [50001]
    unsigned* bsum  = meta + 150016;                      // [49]
    unsigned* elist = meta + 150144;                      // [800000]

    (void)hipMemsetAsync(cnt, 0, 100000 * sizeof(unsigned), stream);   // cnt + cur
    prep_all<<<6410, 256, 0, stream>>>(x, xb, W1, W2, wpk, ei, cnt);
    csr_scan1<<<49, 1024, 0, stream>>>(cnt, offs, bsum);
    csr_scan2<<<1, 64, 0, stream>>>(bsum);
    csr_scan3<<<49, 1024, 0, stream>>>(cnt, offs, bsum);
    csr_place<<<NEDGES / 256, 256, 0, stream>>>(ei, offs, cur, elist);
    edgeconv_main<<<NBLK, 1024, 0, stream>>>(xb, ei, ea, wpk, b1, b2, outp);
    agg_max<<<(NNODES + 3) / 4, 256, 0, stream>>>(offs, elist, outp, aggp);
}